// Round 1
// baseline (13313.472 us; speedup 1.0000x reference)
//
#include <hip/hip_runtime.h>
#include <hip/hip_bf16.h>
#include <math.h>

// Problem dims (fixed by reference)
#define BATCH 4096
#define SEQ   512
#define FDIM  128    // F
#define DDIM  256    // D = 2F
#define KG    384    // F + D  (gates K)
#define NG    1024   // 4D     (gates N)

typedef __bf16 bf16x8 __attribute__((ext_vector_type(8)));
typedef float  f32x4  __attribute__((ext_vector_type(4)));

__device__ __forceinline__ f32x4 mfma16(bf16x8 a, bf16x8 b, f32x4 c) {
    return __builtin_amdgcn_mfma_f32_16x16x32_bf16(a, b, c, 0, 0, 0);
}

__device__ __forceinline__ float sigmoidf_(float x) {
    return 1.0f / (1.0f + __expf(-x));
}

__device__ __forceinline__ float gelu_erf(float v) {
    return 0.5f * v * (1.0f + erff(v * 0.70710678118654752f));
}

// ---------------- prep: pack weights to bf16, combine biases ----------------
__global__ void prep_weights(const float* __restrict__ w_ih, const float* __restrict__ w_hh,
                             const float* __restrict__ b_ih, const float* __restrict__ b_hh,
                             const float* __restrict__ out_w, const float* __restrict__ z_w,
                             __bf16* __restrict__ Wg, __bf16* __restrict__ Wout,
                             __bf16* __restrict__ Wz, float* __restrict__ bg)
{
    int i = blockIdx.x * blockDim.x + threadIdx.x;
    if (i < NG * KG) {
        int n = i / KG, k = i - n * KG;
        float v = (k < FDIM) ? w_ih[n * FDIM + k] : w_hh[n * DDIM + (k - FDIM)];
        Wg[i] = (__bf16)v;
    }
    if (i < FDIM * DDIM) Wout[i] = (__bf16)out_w[i];
    if (i < DDIM * FDIM) Wz[i]   = (__bf16)z_w[i];
    if (i < NG)          bg[i]   = b_ih[i] + b_hh[i];
}

// ---------------- preamble MLP: y[m][n] = act(sum_k x[m][k]*W[n][k] + b[n]) ----------------
template<int K, int N, int ACT>
__global__ void rowmlp(const float* __restrict__ x, const float* __restrict__ W,
                       const float* __restrict__ bias, float* __restrict__ y)
{
    __shared__ float xr[K];
    int m = blockIdx.x;
    for (int k = threadIdx.x; k < K; k += blockDim.x) xr[k] = x[(size_t)m * K + k];
    __syncthreads();
    for (int n = threadIdx.x; n < N; n += blockDim.x) {
        const float* wr = W + (size_t)n * K;
        float s = bias[n];
        #pragma unroll 8
        for (int k = 0; k < K; ++k) s += xr[k] * wr[k];
        if (ACT) s = gelu_erf(s);
        y[(size_t)m * N + n] = s;
    }
}

// ---------------- persistent RNN scan: 1 WG per CU, 16 batch rows each ----------------
// LDS block layout for A-fragments: element (r,k) at [((k>>3)*16 + r)*8 + (k&7)]
// A-frag (16x32 tile kt): lane reads 8 consecutive bf16 at group g = kt*4 + (lane>>4), row lane&15.
__global__ __launch_bounds__(512, 2)
void rnn_main(const float* __restrict__ eps,
              const __bf16* __restrict__ Wg, const float* __restrict__ bg,
              const __bf16* __restrict__ Wout, const float* __restrict__ ob,
              const __bf16* __restrict__ Wz, const float* __restrict__ zb,
              const float* __restrict__ x0, const float* __restrict__ h0,
              float* __restrict__ out)
{
    __shared__ __align__(16) __bf16 xbuf[16 * 16 * 8];  // x: 128 cols -> 16 groups
    __shared__ __align__(16) __bf16 hbuf[32 * 16 * 8];  // h: 256 cols -> 32 groups
    __shared__ __align__(16) __bf16 gbuf[16 * 16 * 8];  // gelu(out): 128 cols

    const int tid  = threadIdx.x;
    const int wv   = tid >> 6;      // wave 0..7
    const int lane = tid & 63;
    const int lo   = lane & 15;
    const int hi   = lane >> 4;
    const int row0 = blockIdx.x * 16;

    // ---- init state ----
    for (int e = tid; e < 16 * 128; e += 512) {
        int r = e >> 7, k = e & 127;
        xbuf[(((k >> 3) << 4) + r) * 8 + (k & 7)] = (__bf16)x0[(size_t)(row0 + r) * 128 + k];
    }
    for (int e = tid; e < 16 * 256; e += 512) {
        int r = e >> 8, k = e & 255;
        hbuf[(((k >> 3) << 4) + r) * 8 + (k & 7)] = (__bf16)h0[(size_t)(row0 + r) * 256 + k];
    }
    // c lives in registers in D-fragment layout: rows hi*4+j, col d=(2*wv+p)*16+lo
    float c[2][4];
    #pragma unroll
    for (int p = 0; p < 2; ++p)
        #pragma unroll
        for (int j = 0; j < 4; ++j)
            c[p][j] = tanhf(h0[(size_t)(row0 + hi * 4 + j) * 256 + (2 * wv + p) * 16 + lo]);

    // biases per lane (col-indexed; same for all 4 rows of a fragment)
    float biasq[8];
    #pragma unroll
    for (int q = 0; q < 8; ++q) {
        int tile = (q >> 1) * 16 + 2 * wv + (q & 1);   // gate (q>>1), half (q&1)
        biasq[q] = bg[tile * 16 + lo];
    }
    const float bo  = ob[wv * 16 + lo];
    const float bmu = zb[wv * 16 + lo];
    const float bls = zb[128 + wv * 16 + lo];

    __syncthreads();

    for (int t = 0; t < SEQ; ++t) {
        // prefetch eps for this step (used at the very end)
        float ev[4];
        #pragma unroll
        for (int j = 0; j < 4; ++j)
            ev[j] = eps[((size_t)t * BATCH + row0 + hi * 4 + j) * 128 + wv * 16 + lo];

        // ---- gates = [x|h] @ Wg^T + b ----
        f32x4 acc[8];
        #pragma unroll
        for (int q = 0; q < 8; ++q) acc[q] = (f32x4){biasq[q], biasq[q], biasq[q], biasq[q]};

        #pragma unroll 2
        for (int kt = 0; kt < 4; ++kt) {            // K-tiles from x
            bf16x8 a = *(const bf16x8*)&xbuf[(((kt * 4 + hi) << 4) + lo) * 8];
            const __bf16* wp = Wg + (size_t)kt * 32 + hi * 8;
            #pragma unroll
            for (int q = 0; q < 8; ++q) {
                int tile = (q >> 1) * 16 + 2 * wv + (q & 1);
                bf16x8 b = *(const bf16x8*)(wp + (size_t)(tile * 16 + lo) * KG);
                acc[q] = mfma16(a, b, acc[q]);
            }
        }
        #pragma unroll 2
        for (int kt = 0; kt < 8; ++kt) {            // K-tiles from h
            bf16x8 a = *(const bf16x8*)&hbuf[(((kt * 4 + hi) << 4) + lo) * 8];
            const __bf16* wp = Wg + (size_t)(kt + 4) * 32 + hi * 8;
            #pragma unroll
            for (int q = 0; q < 8; ++q) {
                int tile = (q >> 1) * 16 + 2 * wv + (q & 1);
                bf16x8 b = *(const bf16x8*)(wp + (size_t)(tile * 16 + lo) * KG);
                acc[q] = mfma16(a, b, acc[q]);
            }
        }

        // ---- lane-local LSTM cell update (acc order: i0 i1 f0 f1 g0 g1 o0 o1) ----
        float hn[2][4];
        #pragma unroll
        for (int p = 0; p < 2; ++p)
            #pragma unroll
            for (int j = 0; j < 4; ++j) {
                float iv = sigmoidf_(acc[0 + p][j]);
                float fv = sigmoidf_(acc[2 + p][j]);
                float gv = tanhf(acc[4 + p][j]);
                float ov = sigmoidf_(acc[6 + p][j]);
                float cn = fv * c[p][j] + iv * gv;
                c[p][j] = cn;
                hn[p][j] = ov * tanhf(cn);
            }
        __syncthreads();   // all waves done reading hbuf/xbuf for gates
        #pragma unroll
        for (int p = 0; p < 2; ++p)
            #pragma unroll
            for (int j = 0; j < 4; ++j) {
                int d = (2 * wv + p) * 16 + lo, r = hi * 4 + j;
                hbuf[(((d >> 3) << 4) + r) * 8 + (d & 7)] = (__bf16)hn[p][j];
            }
        __syncthreads();   // new h visible

        // ---- out = h @ Wout^T + ob (wave wv owns out cols [wv*16, wv*16+16)) ----
        f32x4 ao = (f32x4){bo, bo, bo, bo};
        #pragma unroll 2
        for (int kt = 0; kt < 8; ++kt) {
            bf16x8 a = *(const bf16x8*)&hbuf[(((kt * 4 + hi) << 4) + lo) * 8];
            bf16x8 b = *(const bf16x8*)(Wout + (size_t)(wv * 16 + lo) * 256 + kt * 32 + hi * 8);
            ao = mfma16(a, b, ao);
        }
        #pragma unroll
        for (int j = 0; j < 4; ++j) {
            int d = wv * 16 + lo, r = hi * 4 + j;
            gbuf[(((d >> 3) << 4) + r) * 8 + (d & 7)] = (__bf16)gelu_erf(ao[j]);
        }
        __syncthreads();   // gelu(out) visible

        // ---- z = gelu(out) @ Wz^T + zb ; mu tiles 0..7, logsigma tiles 8..15 ----
        f32x4 amu = (f32x4){bmu, bmu, bmu, bmu};
        f32x4 als = (f32x4){bls, bls, bls, bls};
        #pragma unroll
        for (int kt = 0; kt < 4; ++kt) {
            bf16x8 a  = *(const bf16x8*)&gbuf[(((kt * 4 + hi) << 4) + lo) * 8];
            bf16x8 b0 = *(const bf16x8*)(Wz + (size_t)(wv * 16 + lo) * 128 + kt * 32 + hi * 8);
            bf16x8 b1 = *(const bf16x8*)(Wz + (size_t)((8 + wv) * 16 + lo) * 128 + kt * 32 + hi * 8);
            amu = mfma16(a, b0, amu);
            als = mfma16(a, b1, als);
        }
        #pragma unroll
        for (int j = 0; j < 4; ++j) {
            float smp = amu[j] + __expf(als[j]) * ev[j];
            int d = wv * 16 + lo, r = hi * 4 + j;
            xbuf[(((d >> 3) << 4) + r) * 8 + (d & 7)] = (__bf16)smp;  // next step's input
            out[(size_t)(row0 + r) * (SEQ * 128) + (size_t)t * 128 + d] = smp;
        }
        __syncthreads();   // xbuf ready for next step
    }
}

// ---------------- launch ----------------
extern "C" void kernel_launch(void* const* d_in, const int* in_sizes, int n_in,
                              void* d_out, int out_size, void* d_ws, size_t ws_size,
                              hipStream_t stream)
{
    const float* noise = (const float*)d_in[0];
    const float* eps   = (const float*)d_in[1];
    const float* w1 = (const float*)d_in[2];  const float* b1 = (const float*)d_in[3];
    const float* w2 = (const float*)d_in[4];  const float* b2 = (const float*)d_in[5];
    const float* w3 = (const float*)d_in[6];  const float* b3 = (const float*)d_in[7];
    const float* hw = (const float*)d_in[8];  const float* hb = (const float*)d_in[9];
    const float* wih = (const float*)d_in[10]; const float* bih = (const float*)d_in[11];
    const float* whh = (const float*)d_in[12]; const float* bhh = (const float*)d_in[13];
    const float* ow = (const float*)d_in[14]; const float* ob = (const float*)d_in[15];
    const float* zw = (const float*)d_in[16]; const float* zb = (const float*)d_in[17];
    float* out = (float*)d_out;

    char* ws = (char*)d_ws;
    __bf16* Wg   = (__bf16*)(ws);                         // 1024*384*2 = 786432 B
    __bf16* Wout = (__bf16*)(ws + 786432);                // 128*256*2  = 65536 B
    __bf16* Wz   = (__bf16*)(ws + 851968);                // 256*128*2  = 65536 B
    float*  bg   = (float*) (ws + 917504);                // 1024*4     = 4096 B
    float*  t0   = (float*) (ws + 921600);                // 4096*128*4 = 2 MiB
    float*  t1   = (float*) (ws + 921600 + 2097152);      // 2 MiB
    float*  hid  = (float*) (ws + 921600 + 2 * 2097152);  // 4096*256*4 = 4 MiB

    prep_weights<<<1536, 256, 0, stream>>>(wih, whh, bih, bhh, ow, zw, Wg, Wout, Wz, bg);

    rowmlp<128, 128, 1><<<4096, 128, 0, stream>>>(noise, w1, b1, t0);
    rowmlp<128, 128, 1><<<4096, 128, 0, stream>>>(t0, w2, b2, t1);
    rowmlp<128, 128, 0><<<4096, 128, 0, stream>>>(t1, w3, b3, t0);   // inputs
    rowmlp<128, 256, 0><<<4096, 256, 0, stream>>>(t0, hw, hb, hid);  // hidden

    rnn_main<<<256, 512, 0, stream>>>(eps, Wg, bg, Wout, ob, Wz, zb, t0, hid, out);
}

// Round 2
// 9900.029 us; speedup vs baseline: 1.3448x; 1.3448x over previous
//
#include <hip/hip_runtime.h>
#include <hip/hip_bf16.h>
#include <math.h>

// Problem dims (fixed by reference)
#define BATCH 4096
#define SEQ   512
#define FDIM  128    // F
#define DDIM  256    // D = 2F
#define KG    384    // F + D  (gates K)
#define NG    1024   // 4D     (gates N)

typedef __bf16 bf16x8 __attribute__((ext_vector_type(8)));
typedef float  f32x4  __attribute__((ext_vector_type(4)));

__device__ __forceinline__ f32x4 mfma16(bf16x8 a, bf16x8 b, f32x4 c) {
    return __builtin_amdgcn_mfma_f32_16x16x32_bf16(a, b, c, 0, 0, 0);
}

__device__ __forceinline__ float rcp_(float x) { return __builtin_amdgcn_rcpf(x); }
__device__ __forceinline__ float sigmoid_(float x) { return rcp_(1.0f + __expf(-x)); }
__device__ __forceinline__ float tanh_(float x) {
    // tanh(|x|) = 1 - 2e/(1+e), e = exp(-2|x|)  (numerically stable)
    float e = __expf(-2.0f * fabsf(x));
    float t = 1.0f - 2.0f * e * rcp_(1.0f + e);
    return copysignf(t, x);
}
__device__ __forceinline__ float gelu_erf(float v) {
    return 0.5f * v * (1.0f + erff(v * 0.70710678118654752f));
}

// ---------------- prep: pack weights to bf16, combine biases ----------------
__global__ void prep_weights(const float* __restrict__ w_ih, const float* __restrict__ w_hh,
                             const float* __restrict__ b_ih, const float* __restrict__ b_hh,
                             const float* __restrict__ out_w, const float* __restrict__ z_w,
                             __bf16* __restrict__ Wg, __bf16* __restrict__ Wout,
                             __bf16* __restrict__ Wz, float* __restrict__ bg)
{
    int i = blockIdx.x * blockDim.x + threadIdx.x;
    if (i < NG * KG) {
        int n = i / KG, k = i - n * KG;
        float v = (k < FDIM) ? w_ih[n * FDIM + k] : w_hh[n * DDIM + (k - FDIM)];
        Wg[i] = (__bf16)v;
    }
    if (i < FDIM * DDIM) Wout[i] = (__bf16)out_w[i];
    if (i < DDIM * FDIM) Wz[i]   = (__bf16)z_w[i];
    if (i < NG)          bg[i]   = b_ih[i] + b_hh[i];
}

// ---------------- preamble MLP ----------------
template<int K, int N, int ACT>
__global__ void rowmlp(const float* __restrict__ x, const float* __restrict__ W,
                       const float* __restrict__ bias, float* __restrict__ y)
{
    __shared__ float xr[K];
    int m = blockIdx.x;
    for (int k = threadIdx.x; k < K; k += blockDim.x) xr[k] = x[(size_t)m * K + k];
    __syncthreads();
    for (int n = threadIdx.x; n < N; n += blockDim.x) {
        const float* wr = W + (size_t)n * K;
        float s = bias[n];
        #pragma unroll 8
        for (int k = 0; k < K; ++k) s += xr[k] * wr[k];
        if (ACT) s = gelu_erf(s);
        y[(size_t)m * N + n] = s;
    }
}

// ---------------- persistent RNN scan: 1 WG/CU, 16 batch rows each ----------------
// A-frag LDS block layout: element (r,k) at byte ((k>>3)*16 + r)*16 + (k&7)*2
// Weight residency: Wout(8 frags) + Wz(8) + Wg kt=10,11 (16) in VGPRs;
//                   Wg kt=8,9 in LDS (128 KB); Wg kt=0..7 streamed from L2.
__global__ __launch_bounds__(512, 2)
void rnn_main(const float* __restrict__ eps,
              const __bf16* __restrict__ Wg, const float* __restrict__ bg,
              const __bf16* __restrict__ Wout, const float* __restrict__ ob,
              const __bf16* __restrict__ Wz, const float* __restrict__ zb,
              const float* __restrict__ x0, const float* __restrict__ h0,
              float* __restrict__ out)
{
    extern __shared__ __align__(16) char smem[];
    __bf16* xbuf  = (__bf16*)smem;       // 2048 el  (4 KB)   x: 16 kgroups
    __bf16* hbufA = xbuf  + 2048;        // 4096 el  (8 KB)   h double-buffer
    __bf16* hbufB = hbufA + 4096;        // 4096 el  (8 KB)
    __bf16* gbuf  = hbufB + 4096;        // 2048 el  (4 KB)   gelu(out)
    char*   wlds  = (char*)(gbuf + 2048);// 128 KB: [kt2][wave][q][lane*16]

    const int tid  = threadIdx.x;
    const int wv   = tid >> 6;
    const int lane = tid & 63;
    const int lo   = lane & 15;
    const int hi   = lane >> 4;
    const int row0 = blockIdx.x * 16;
    const int abase = (hi * 16 + lo) * 16;          // A-frag byte offset within kt-block

    // ---- init activations ----
    for (int e = tid; e < 16 * 128; e += 512) {
        int r = e >> 7, k = e & 127;
        xbuf[(((k >> 3) << 4) + r) * 8 + (k & 7)] = (__bf16)x0[(size_t)(row0 + r) * 128 + k];
    }
    for (int e = tid; e < 16 * 256; e += 512) {
        int r = e >> 8, k = e & 255;
        hbufA[(((k >> 3) << 4) + r) * 8 + (k & 7)] = (__bf16)h0[(size_t)(row0 + r) * 256 + k];
    }
    float c[2][4];
    #pragma unroll
    for (int p = 0; p < 2; ++p)
        #pragma unroll
        for (int j = 0; j < 4; ++j)
            c[p][j] = tanh_(h0[(size_t)(row0 + hi * 4 + j) * 256 + (2 * wv + p) * 16 + lo]);

    // ---- per-q weight row base pointers + biases ----
    const __bf16* wgbase[8];
    float biasq[8];
    #pragma unroll
    for (int q = 0; q < 8; ++q) {
        int tile = (q >> 1) * 16 + 2 * wv + (q & 1);
        wgbase[q] = Wg + (size_t)(tile * 16 + lo) * KG + hi * 8;
        biasq[q]  = bg[tile * 16 + lo];
    }
    const float bo  = ob[wv * 16 + lo];
    const float bmu = zb[wv * 16 + lo];
    const float bls = zb[128 + wv * 16 + lo];

    // ---- resident weights: VGPRs ----
    bf16x8 wout[8];
    #pragma unroll
    for (int kt = 0; kt < 8; ++kt)
        wout[kt] = *(const bf16x8*)(Wout + (size_t)(wv * 16 + lo) * 256 + kt * 32 + hi * 8);
    bf16x8 wz0[4], wz1[4];
    #pragma unroll
    for (int kt = 0; kt < 4; ++kt) {
        wz0[kt] = *(const bf16x8*)(Wz + (size_t)(wv * 16 + lo) * 128 + kt * 32 + hi * 8);
        wz1[kt] = *(const bf16x8*)(Wz + (size_t)((8 + wv) * 16 + lo) * 128 + kt * 32 + hi * 8);
    }
    bf16x8 wgr[2][8];   // Wg kt = 10, 11
    #pragma unroll
    for (int q = 0; q < 8; ++q) {
        wgr[0][q] = *(const bf16x8*)(wgbase[q] + 10 * 32);
        wgr[1][q] = *(const bf16x8*)(wgbase[q] + 11 * 32);
    }
    // ---- resident weights: LDS (Wg kt = 8, 9) ----
    char* wbase = wlds + wv * 8192 + lane * 16;
    #pragma unroll
    for (int kt2 = 0; kt2 < 2; ++kt2)
        #pragma unroll
        for (int q = 0; q < 8; ++q) {
            bf16x8 w = *(const bf16x8*)(wgbase[q] + (8 + kt2) * 32);
            *(bf16x8*)(wbase + kt2 * 65536 + q * 1024) = w;
        }

    __syncthreads();

    __bf16* hb_cur = hbufA;
    __bf16* hb_nxt = hbufB;

    for (int t = 0; t < SEQ; ++t) {
        // prefetch eps (consumed at step end)
        float ev[4];
        #pragma unroll
        for (int j = 0; j < 4; ++j)
            ev[j] = eps[((size_t)t * BATCH + row0 + hi * 4 + j) * 128 + wv * 16 + lo];

        // ---- gates = [x|h] @ Wg^T + b ----
        f32x4 acc[8];
        #pragma unroll
        for (int q = 0; q < 8; ++q) acc[q] = (f32x4){biasq[q], biasq[q], biasq[q], biasq[q]};

        #pragma unroll 2
        for (int kt = 0; kt < 4; ++kt) {            // x part (streamed)
            bf16x8 a = *(const bf16x8*)((char*)xbuf + kt * 1024 + abase);
            #pragma unroll
            for (int q = 0; q < 8; ++q) {
                bf16x8 b = *(const bf16x8*)(wgbase[q] + kt * 32);
                acc[q] = mfma16(a, b, acc[q]);
            }
        }
        #pragma unroll 2
        for (int kt = 0; kt < 4; ++kt) {            // h part kt 4..7 (streamed)
            bf16x8 a = *(const bf16x8*)((char*)hb_cur + kt * 1024 + abase);
            #pragma unroll
            for (int q = 0; q < 8; ++q) {
                bf16x8 b = *(const bf16x8*)(wgbase[q] + (4 + kt) * 32);
                acc[q] = mfma16(a, b, acc[q]);
            }
        }
        #pragma unroll
        for (int kt2 = 0; kt2 < 2; ++kt2) {         // h part kt 8,9 (LDS-resident)
            bf16x8 a = *(const bf16x8*)((char*)hb_cur + (4 + kt2) * 1024 + abase);
            #pragma unroll
            for (int q = 0; q < 8; ++q) {
                bf16x8 b = *(const bf16x8*)(wbase + kt2 * 65536 + q * 1024);
                acc[q] = mfma16(a, b, acc[q]);
            }
        }
        #pragma unroll
        for (int kt2 = 0; kt2 < 2; ++kt2) {         // h part kt 10,11 (reg-resident)
            bf16x8 a = *(const bf16x8*)((char*)hb_cur + (6 + kt2) * 1024 + abase);
            #pragma unroll
            for (int q = 0; q < 8; ++q)
                acc[q] = mfma16(a, wgr[kt2][q], acc[q]);
        }

        // ---- lane-local LSTM cell (acc order: i0 i1 f0 f1 g0 g1 o0 o1) ----
        #pragma unroll
        for (int p = 0; p < 2; ++p)
            #pragma unroll
            for (int j = 0; j < 4; ++j) {
                float iv = sigmoid_(acc[0 + p][j]);
                float fv = sigmoid_(acc[2 + p][j]);
                float gv = tanh_(acc[4 + p][j]);
                float ov = sigmoid_(acc[6 + p][j]);
                float cn = fv * c[p][j] + iv * gv;
                c[p][j] = cn;
                float hv = ov * tanh_(cn);
                int d = (2 * wv + p) * 16 + lo, r = hi * 4 + j;
                hb_nxt[(((d >> 3) << 4) + r) * 8 + (d & 7)] = (__bf16)hv;
            }
        __syncthreads();   // (1) new h visible

        // ---- out = h @ Wout^T + ob (load-free: wout resident) ----
        f32x4 ao0 = (f32x4){bo, bo, bo, bo};
        f32x4 ao1 = (f32x4){0.f, 0.f, 0.f, 0.f};
        #pragma unroll
        for (int kt = 0; kt < 4; ++kt) {
            bf16x8 a0 = *(const bf16x8*)((char*)hb_nxt + (2 * kt) * 1024 + abase);
            bf16x8 a1 = *(const bf16x8*)((char*)hb_nxt + (2 * kt + 1) * 1024 + abase);
            ao0 = mfma16(a0, wout[2 * kt], ao0);
            ao1 = mfma16(a1, wout[2 * kt + 1], ao1);
        }
        #pragma unroll
        for (int j = 0; j < 4; ++j) {
            int d = wv * 16 + lo, r = hi * 4 + j;
            gbuf[(((d >> 3) << 4) + r) * 8 + (d & 7)] = (__bf16)gelu_erf(ao0[j] + ao1[j]);
        }
        __syncthreads();   // (2) gelu(out) visible

        // ---- z = gelu(out) @ Wz^T + zb (load-free: wz resident) ----
        f32x4 amu = (f32x4){bmu, bmu, bmu, bmu};
        f32x4 als = (f32x4){bls, bls, bls, bls};
        #pragma unroll
        for (int kt = 0; kt < 4; ++kt) {
            bf16x8 a = *(const bf16x8*)((char*)gbuf + kt * 1024 + abase);
            amu = mfma16(a, wz0[kt], amu);
            als = mfma16(a, wz1[kt], als);
        }
        #pragma unroll
        for (int j = 0; j < 4; ++j) {
            float smp = amu[j] + __expf(als[j]) * ev[j];
            int d = wv * 16 + lo, r = hi * 4 + j;
            xbuf[(((d >> 3) << 4) + r) * 8 + (d & 7)] = (__bf16)smp;
            out[(size_t)(row0 + r) * (SEQ * 128) + (size_t)t * 128 + d] = smp;
        }
        __syncthreads();   // (3) xbuf ready for next step

        __bf16* tmp = hb_cur; hb_cur = hb_nxt; hb_nxt = tmp;
    }
}

// ---------------- launch ----------------
extern "C" void kernel_launch(void* const* d_in, const int* in_sizes, int n_in,
                              void* d_out, int out_size, void* d_ws, size_t ws_size,
                              hipStream_t stream)
{
    const float* noise = (const float*)d_in[0];
    const float* eps   = (const float*)d_in[1];
    const float* w1 = (const float*)d_in[2];  const float* b1 = (const float*)d_in[3];
    const float* w2 = (const float*)d_in[4];  const float* b2 = (const float*)d_in[5];
    const float* w3 = (const float*)d_in[6];  const float* b3 = (const float*)d_in[7];
    const float* hw = (const float*)d_in[8];  const float* hb = (const float*)d_in[9];
    const float* wih = (const float*)d_in[10]; const float* bih = (const float*)d_in[11];
    const float* whh = (const float*)d_in[12]; const float* bhh = (const float*)d_in[13];
    const float* ow = (const float*)d_in[14]; const float* ob = (const float*)d_in[15];
    const float* zw = (const float*)d_in[16]; const float* zb = (const float*)d_in[17];
    float* out = (float*)d_out;

    char* ws = (char*)d_ws;
    __bf16* Wg   = (__bf16*)(ws);                         // 786432 B
    __bf16* Wout = (__bf16*)(ws + 786432);                // 65536 B
    __bf16* Wz   = (__bf16*)(ws + 851968);                // 65536 B
    float*  bg   = (float*) (ws + 917504);                // 4096 B
    float*  t0   = (float*) (ws + 921600);                // 2 MiB
    float*  t1   = (float*) (ws + 921600 + 2097152);      // 2 MiB
    float*  hid  = (float*) (ws + 921600 + 2 * 2097152);  // 4 MiB

    prep_weights<<<1536, 256, 0, stream>>>(wih, whh, bih, bhh, ow, zw, Wg, Wout, Wz, bg);

    rowmlp<128, 128, 1><<<4096, 128, 0, stream>>>(noise, w1, b1, t0);
    rowmlp<128, 128, 1><<<4096, 128, 0, stream>>>(t0, w2, b2, t1);
    rowmlp<128, 128, 0><<<4096, 128, 0, stream>>>(t1, w3, b3, t0);   // inputs
    rowmlp<128, 256, 0><<<4096, 256, 0, stream>>>(t0, hw, hb, hid);  // hidden

    // dynamic LDS: 24576 B activation buffers + 131072 B resident Wg kt=8,9
    rnn_main<<<256, 512, 155648, stream>>>(eps, Wg, bg, Wout, ob, Wz, zb, t0, hid, out);
}